// Round 1
// baseline (1407.921 us; speedup 1.0000x reference)
//
#include <hip/hip_runtime.h>

#define N_NODES 100000
#define N_EDGES 1600000
#define F 64
#define NCLS 16
#define K1 8

// ---------------- degree / normalization ----------------

__global__ void k_deg(const int* __restrict__ ei, int* __restrict__ deg) {
    int e = blockIdx.x * blockDim.x + threadIdx.x;
    if (e >= N_EDGES) return;
    int r = ei[e], c = ei[N_EDGES + e];
    if (r != c) atomicAdd(&deg[r], 1);
}

__global__ void k_dinv(const int* __restrict__ deg, float* __restrict__ dinv) {
    int i = blockIdx.x * blockDim.x + threadIdx.x;
    if (i >= N_NODES) return;
    int d = deg[i];
    dinv[i] = d > 0 ? rsqrtf((float)d) : 0.f;
}

// ---------------- exclusive scan (rowptr) ----------------
// scan1: each block scans 1024 ints of deg -> block-local exclusive into rowptr, total into bsum
__global__ void k_scan1(const int* __restrict__ deg, int* __restrict__ rowptr, int* __restrict__ bsum) {
    __shared__ int sd[256];
    int tid = threadIdx.x;
    int base = blockIdx.x * 1024 + tid * 4;
    int v[4];
#pragma unroll
    for (int j = 0; j < 4; j++) {
        int idx = base + j;
        v[j] = (idx < N_NODES) ? deg[idx] : 0;
    }
    int s = v[0] + v[1] + v[2] + v[3];
    sd[tid] = s;
    __syncthreads();
    for (int d = 1; d < 256; d <<= 1) {
        int t = (tid >= d) ? sd[tid - d] : 0;
        __syncthreads();
        sd[tid] += t;
        __syncthreads();
    }
    int excl = sd[tid] - s;
    if (tid == 255) bsum[blockIdx.x] = sd[255];
    int run = excl;
#pragma unroll
    for (int j = 0; j < 4; j++) {
        int idx = base + j;
        if (idx < N_NODES) rowptr[idx] = run;
        run += v[j];
    }
}

__global__ void k_scan2(int* __restrict__ bsum, int* __restrict__ rowptr, int nblk) {
    if (threadIdx.x == 0 && blockIdx.x == 0) {
        int acc = 0;
        for (int b = 0; b < nblk; b++) { int t = bsum[b]; bsum[b] = acc; acc += t; }
        rowptr[N_NODES] = acc;
    }
}

__global__ void k_scan3(int* __restrict__ rowptr, const int* __restrict__ bsum) {
    int tid = threadIdx.x;
    int base = blockIdx.x * 1024 + tid * 4;
    int off = bsum[blockIdx.x];
#pragma unroll
    for (int j = 0; j < 4; j++) {
        int idx = base + j;
        if (idx < N_NODES) rowptr[idx] += off;
    }
}

// ---------------- CSR fill ----------------
__global__ void k_fill(const int* __restrict__ ei, const float* __restrict__ dinv,
                       const int* __restrict__ rowptr, int* __restrict__ cursor,
                       int* __restrict__ csr_col, float* __restrict__ csr_w) {
    int e = blockIdx.x * blockDim.x + threadIdx.x;
    if (e >= N_EDGES) return;
    int r = ei[e], c = ei[N_EDGES + e];
    if (r == c) return;
    int p = rowptr[r] + atomicAdd(&cursor[r], 1);
    csr_col[p] = c;
    csr_w[p] = -dinv[r] * dinv[c];
}

// ---------------- propagation: dst = alpha * (L_hat @ src) - beta * prev ----------------
// one wave (64 lanes) per node, lane = feature
__global__ __launch_bounds__(256) void k_prop(const int* __restrict__ rowptr,
                                              const int* __restrict__ csr_col,
                                              const float* __restrict__ csr_w,
                                              const float* __restrict__ src,
                                              const float* __restrict__ prev,
                                              float* __restrict__ dst,
                                              float alpha, float beta) {
    int wid = (int)((blockIdx.x * blockDim.x + threadIdx.x) >> 6);
    int lane = threadIdx.x & 63;
    if (wid >= N_NODES) return;
    int beg = rowptr[wid], end = rowptr[wid + 1];
    float acc = 0.f;
    for (int j = beg; j < end; j++) {
        int c = csr_col[j];
        float w = csr_w[j];
        acc = fmaf(w, src[(size_t)c * F + lane], acc);
    }
    float res = alpha * acc;
    if (beta != 0.f) res -= beta * prev[(size_t)wid * F + lane];
    dst[(size_t)wid * F + lane] = res;
}

// ---------------- tiled GEMM accumulate: out(64-row tile) (+)= T @ W(64x64) ----------------
__global__ __launch_bounds__(256) void k_gemm(const float* __restrict__ T,
                                              const float* __restrict__ W,
                                              float* __restrict__ out, int init) {
    __shared__ float Tt[64][65];
    __shared__ float Wl[64][64];
    int tid = threadIdx.x;
    int base = blockIdx.x * 64;
#pragma unroll
    for (int j = 0; j < 4; j++) {
        int e = j * 1024 + tid * 4;
        int r = e >> 6, c = e & 63;
        int gr = base + r;
        float4 v = make_float4(0.f, 0.f, 0.f, 0.f);
        if (gr < N_NODES) v = *(const float4*)&T[(size_t)gr * 64 + c];
        Tt[r][c] = v.x; Tt[r][c + 1] = v.y; Tt[r][c + 2] = v.z; Tt[r][c + 3] = v.w;
        *(float4*)&Wl[r][c] = *(const float4*)&W[e];
    }
    __syncthreads();
    int r0 = (tid >> 4) * 4, c0 = (tid & 15) * 4;
    float acc[4][4] = {};
    for (int kk = 0; kk < 64; kk++) {
        float a0 = Tt[r0][kk], a1 = Tt[r0 + 1][kk], a2 = Tt[r0 + 2][kk], a3 = Tt[r0 + 3][kk];
        float4 b = *(const float4*)&Wl[kk][c0];
        acc[0][0] = fmaf(a0, b.x, acc[0][0]); acc[0][1] = fmaf(a0, b.y, acc[0][1]);
        acc[0][2] = fmaf(a0, b.z, acc[0][2]); acc[0][3] = fmaf(a0, b.w, acc[0][3]);
        acc[1][0] = fmaf(a1, b.x, acc[1][0]); acc[1][1] = fmaf(a1, b.y, acc[1][1]);
        acc[1][2] = fmaf(a1, b.z, acc[1][2]); acc[1][3] = fmaf(a1, b.w, acc[1][3]);
        acc[2][0] = fmaf(a2, b.x, acc[2][0]); acc[2][1] = fmaf(a2, b.y, acc[2][1]);
        acc[2][2] = fmaf(a2, b.z, acc[2][2]); acc[2][3] = fmaf(a2, b.w, acc[2][3]);
        acc[3][0] = fmaf(a3, b.x, acc[3][0]); acc[3][1] = fmaf(a3, b.y, acc[3][1]);
        acc[3][2] = fmaf(a3, b.z, acc[3][2]); acc[3][3] = fmaf(a3, b.w, acc[3][3]);
    }
#pragma unroll
    for (int i = 0; i < 4; i++) {
        int gr = base + r0 + i;
        if (gr >= N_NODES) break;
        float4* p = (float4*)&out[(size_t)gr * 64 + c0];
        float4 v = make_float4(acc[i][0], acc[i][1], acc[i][2], acc[i][3]);
        if (!init) {
            float4 o = *p;
            v.x += o.x; v.y += o.y; v.z += o.z; v.w += o.w;
        }
        *p = v;
    }
}

// ---------------- layer2 + softmax epilogue ----------------
// 4 threads per node (each 4 output classes), 64 nodes per block
__global__ __launch_bounds__(256) void k_final(const float* __restrict__ out_acc,
                                               const float* __restrict__ b1,
                                               const float* __restrict__ W2,
                                               const float* __restrict__ b2,
                                               float* __restrict__ y) {
    __shared__ float Wl[64 * 16];
    __shared__ float b1l[64];
    int tid = threadIdx.x;
    for (int j = tid; j < 64 * 16; j += 256) Wl[j] = W2[j];
    if (tid < 64) b1l[tid] = b1[tid];
    __syncthreads();
    int node = blockIdx.x * 64 + (tid >> 2);
    int cg = tid & 3;
    if (node >= N_NODES) return;
    float l0 = b2[cg * 4 + 0], l1 = b2[cg * 4 + 1], l2 = b2[cg * 4 + 2], l3 = b2[cg * 4 + 3];
    const float* row = &out_acc[(size_t)node * 64];
    for (int f = 0; f < 64; f++) {
        float h = row[f] + b1l[f];
        h = h > 0.f ? h : 0.f;
        l0 = fmaf(h, Wl[f * 16 + cg * 4 + 0], l0);
        l1 = fmaf(h, Wl[f * 16 + cg * 4 + 1], l1);
        l2 = fmaf(h, Wl[f * 16 + cg * 4 + 2], l2);
        l3 = fmaf(h, Wl[f * 16 + cg * 4 + 3], l3);
    }
    float m = fmaxf(fmaxf(l0, l1), fmaxf(l2, l3));
    m = fmaxf(m, __shfl_xor(m, 1, 64));
    m = fmaxf(m, __shfl_xor(m, 2, 64));
    float e0 = expf(l0 - m), e1 = expf(l1 - m), e2 = expf(l2 - m), e3 = expf(l3 - m);
    float s = e0 + e1 + e2 + e3;
    s += __shfl_xor(s, 1, 64);
    s += __shfl_xor(s, 2, 64);
    float inv = 1.f / s;
    float4 o = make_float4(e0 * inv, e1 * inv, e2 * inv, e3 * inv);
    *(float4*)&y[(size_t)node * 16 + cg * 4] = o;
}

// ---------------- launch ----------------

extern "C" void kernel_launch(void* const* d_in, const int* in_sizes, int n_in,
                              void* d_out, int out_size, void* d_ws, size_t ws_size,
                              hipStream_t stream) {
    const float* x  = (const float*)d_in[0];
    const int*   ei = (const int*)d_in[1];
    const float* W1 = (const float*)d_in[2];
    const float* b1 = (const float*)d_in[3];
    const float* W2 = (const float*)d_in[4];
    const float* b2 = (const float*)d_in[5];
    float* y = (float*)d_out;

    char* p = (char*)d_ws;
    auto alloc = [&](size_t bytes) {
        char* q = p;
        p += (bytes + 255) & ~(size_t)255;
        return q;
    };
    int*   deg     = (int*)alloc((size_t)N_NODES * 4);
    float* dinv    = (float*)alloc((size_t)N_NODES * 4);
    int*   rowptr  = (int*)alloc((size_t)(N_NODES + 1) * 4);
    int*   bsum    = (int*)alloc(128 * 4);
    int*   cursor  = (int*)alloc((size_t)N_NODES * 4);
    int*   csr_col = (int*)alloc((size_t)N_EDGES * 4);
    float* csr_w   = (float*)alloc((size_t)N_EDGES * 4);
    float* A       = (float*)alloc((size_t)N_NODES * F * 4);
    float* B       = (float*)alloc((size_t)N_NODES * F * 4);
    float* C       = (float*)alloc((size_t)N_NODES * F * 4);
    float* out_acc = (float*)alloc((size_t)N_NODES * F * 4);

    hipMemsetAsync(deg, 0, (size_t)N_NODES * 4, stream);
    hipMemsetAsync(cursor, 0, (size_t)N_NODES * 4, stream);

    int eb = (N_EDGES + 255) / 256;
    int nb = (N_NODES + 255) / 256;
    k_deg<<<eb, 256, 0, stream>>>(ei, deg);
    k_dinv<<<nb, 256, 0, stream>>>(deg, dinv);
    int nblk = (N_NODES + 1023) / 1024;
    k_scan1<<<nblk, 256, 0, stream>>>(deg, rowptr, bsum);
    k_scan2<<<1, 64, 0, stream>>>(bsum, rowptr, nblk);
    k_scan3<<<nblk, 256, 0, stream>>>(rowptr, bsum);
    k_fill<<<eb, 256, 0, stream>>>(ei, dinv, rowptr, cursor, csr_col, csr_w);

    int gemm_blocks = (N_NODES + 63) / 64;
    int prop_blocks = (N_NODES + 3) / 4;

    // k = 0: out = x @ W1[0]
    k_gemm<<<gemm_blocks, 256, 0, stream>>>(x, W1 + 0 * 4096, out_acc, 1);
    // k = 1: tx = prop(x); out += tx @ W1[1]
    k_prop<<<prop_blocks, 256, 0, stream>>>(rowptr, csr_col, csr_w, x, x, B, 1.f, 0.f);
    k_gemm<<<gemm_blocks, 256, 0, stream>>>(B, W1 + 1 * 4096, out_acc, 0);

    const float* txp = x;
    float* tx = B;
    float* fr = C;
    for (int k = 2; k < K1; k++) {
        k_prop<<<prop_blocks, 256, 0, stream>>>(rowptr, csr_col, csr_w, tx, txp, fr, 2.f, 1.f);
        k_gemm<<<gemm_blocks, 256, 0, stream>>>(fr, W1 + k * 4096, out_acc, 0);
        const float* new_txp = tx;
        float* new_fr = (k == 2) ? A : (float*)txp;
        txp = new_txp;
        tx = fr;
        fr = new_fr;
    }

    k_final<<<gemm_blocks, 256, 0, stream>>>(out_acc, b1, W2, b2, y);
}

// Round 2
// 940.451 us; speedup vs baseline: 1.4971x; 1.4971x over previous
//
#include <hip/hip_runtime.h>
#include <hip/hip_fp16.h>

#define N_NODES 100000
#define N_EDGES 1600000
#define F 64
#define NCLS 16
#define K1 8

// ---------------- degree / normalization ----------------

__global__ void k_deg(const int* __restrict__ ei, int* __restrict__ deg) {
    int e = blockIdx.x * blockDim.x + threadIdx.x;
    if (e >= N_EDGES) return;
    int r = ei[e], c = ei[N_EDGES + e];
    if (r != c) atomicAdd(&deg[r], 1);
}

__global__ void k_dinv(const int* __restrict__ deg, float* __restrict__ dinv) {
    int i = blockIdx.x * blockDim.x + threadIdx.x;
    if (i >= N_NODES) return;
    int d = deg[i];
    dinv[i] = d > 0 ? rsqrtf((float)d) : 0.f;
}

// ---------------- exclusive scan (rowptr) ----------------
__global__ void k_scan1(const int* __restrict__ deg, int* __restrict__ rowptr, int* __restrict__ bsum) {
    __shared__ int sd[256];
    int tid = threadIdx.x;
    int base = blockIdx.x * 1024 + tid * 4;
    int v[4];
#pragma unroll
    for (int j = 0; j < 4; j++) {
        int idx = base + j;
        v[j] = (idx < N_NODES) ? deg[idx] : 0;
    }
    int s = v[0] + v[1] + v[2] + v[3];
    sd[tid] = s;
    __syncthreads();
    for (int d = 1; d < 256; d <<= 1) {
        int t = (tid >= d) ? sd[tid - d] : 0;
        __syncthreads();
        sd[tid] += t;
        __syncthreads();
    }
    int excl = sd[tid] - s;
    if (tid == 255) bsum[blockIdx.x] = sd[255];
    int run = excl;
#pragma unroll
    for (int j = 0; j < 4; j++) {
        int idx = base + j;
        if (idx < N_NODES) rowptr[idx] = run;
        run += v[j];
    }
}

__global__ void k_scan2(int* __restrict__ bsum, int* __restrict__ rowptr, int nblk) {
    if (threadIdx.x == 0 && blockIdx.x == 0) {
        int acc = 0;
        for (int b = 0; b < nblk; b++) { int t = bsum[b]; bsum[b] = acc; acc += t; }
        rowptr[N_NODES] = acc;
    }
}

__global__ void k_scan3(int* __restrict__ rowptr, const int* __restrict__ bsum) {
    int tid = threadIdx.x;
    int base = blockIdx.x * 1024 + tid * 4;
    int off = bsum[blockIdx.x];
#pragma unroll
    for (int j = 0; j < 4; j++) {
        int idx = base + j;
        if (idx < N_NODES) rowptr[idx] += off;
    }
}

// ---------------- CSR fill: packed (col, weight_bits) ----------------
__global__ void k_fill(const int* __restrict__ ei, const float* __restrict__ dinv,
                       const int* __restrict__ rowptr, int* __restrict__ cursor,
                       int2* __restrict__ csr_ew) {
    int e = blockIdx.x * blockDim.x + threadIdx.x;
    if (e >= N_EDGES) return;
    int r = ei[e], c = ei[N_EDGES + e];
    if (r == c) return;
    int p = rowptr[r] + atomicAdd(&cursor[r], 1);
    float w = -dinv[r] * dinv[c];
    csr_ew[p] = make_int2(c, __float_as_int(w));
}

// ---------------- x fp32 -> fp16 ----------------
__global__ void k_cvt(const float* __restrict__ x, __half* __restrict__ t0) {
    int i = blockIdx.x * blockDim.x + threadIdx.x;
    int base = i * 4;
    if (base >= N_NODES * F) return;
    float4 v = *(const float4*)&x[base];
    __half2 a = __floats2half2_rn(v.x, v.y);
    __half2 b = __floats2half2_rn(v.z, v.w);
    *(__half2*)&t0[base] = a;
    *(__half2*)&t0[base + 2] = b;
}

// ---------------- propagation: dst = alpha*(L_hat @ src) - beta*prev (fp16 buffers) ----------------
// one wave per node, lane = feature
__global__ __launch_bounds__(256) void k_prop(const int* __restrict__ rowptr,
                                              const int2* __restrict__ csr_ew,
                                              const __half* __restrict__ src,
                                              const __half* __restrict__ prev,
                                              __half* __restrict__ dst,
                                              float alpha, float beta) {
    int wid = (int)((blockIdx.x * blockDim.x + threadIdx.x) >> 6);
    int lane = threadIdx.x & 63;
    if (wid >= N_NODES) return;
    int beg = rowptr[wid], end = rowptr[wid + 1];
    float acc = 0.f;
    int j = beg;
    for (; j + 1 < end; j += 2) {
        int2 e0 = csr_ew[j];
        int2 e1 = csr_ew[j + 1];
        float v0 = __half2float(src[(size_t)e0.x * F + lane]);
        float v1 = __half2float(src[(size_t)e1.x * F + lane]);
        acc = fmaf(__int_as_float(e0.y), v0, acc);
        acc = fmaf(__int_as_float(e1.y), v1, acc);
    }
    if (j < end) {
        int2 e0 = csr_ew[j];
        acc = fmaf(__int_as_float(e0.y), __half2float(src[(size_t)e0.x * F + lane]), acc);
    }
    float res = alpha * acc;
    if (beta != 0.f) res -= beta * __half2float(prev[(size_t)wid * F + lane]);
    dst[(size_t)wid * F + lane] = __float2half(res);
}

// ---------------- fused: out = softmax(relu(sum_k Tx_k @ W1_k + b1) @ W2 + b2) ----------------
// 64-node tile per block, 256 threads, 4x4 micro-tile per thread
__global__ __launch_bounds__(256) void k_fused_out(const __half* __restrict__ T,   // [K1][N][64]
                                                   const float* __restrict__ W1,   // [K1][64][64]
                                                   const float* __restrict__ b1,
                                                   const float* __restrict__ W2,   // [64][16]
                                                   const float* __restrict__ b2,
                                                   float* __restrict__ y) {
    __shared__ float Tt[64][65];
    __shared__ float Wl[64][64];
    __shared__ float W2l[64 * 16];
    __shared__ float b1l[64];
    __shared__ float b2l[16];
    int tid = threadIdx.x;
    int base = blockIdx.x * 64;

    for (int j = tid; j < 64 * 16; j += 256) W2l[j] = W2[j];
    if (tid < 64) b1l[tid] = b1[tid];
    if (tid < 16) b2l[tid] = b2[tid];

    int r0 = (tid >> 4) * 4, c0 = (tid & 15) * 4;
    float acc[4][4] = {};

    for (int k = 0; k < K1; k++) {
        const __half* Tk = T + (size_t)k * N_NODES * F;
        const float* Wk = W1 + (size_t)k * 4096;
        __syncthreads();
#pragma unroll
        for (int j = 0; j < 4; j++) {
            int e = j * 1024 + tid * 4;
            int r = e >> 6, c = e & 63;
            int gr = base + r;
            if (gr < N_NODES) {
                const __half2* p2 = (const __half2*)&Tk[(size_t)gr * F + c];
                float2 fa = __half22float2(p2[0]);
                float2 fb = __half22float2(p2[1]);
                Tt[r][c] = fa.x; Tt[r][c + 1] = fa.y; Tt[r][c + 2] = fb.x; Tt[r][c + 3] = fb.y;
            } else {
                Tt[r][c] = 0.f; Tt[r][c + 1] = 0.f; Tt[r][c + 2] = 0.f; Tt[r][c + 3] = 0.f;
            }
            *(float4*)&Wl[r][c] = *(const float4*)&Wk[e];
        }
        __syncthreads();
        for (int kk = 0; kk < 64; kk++) {
            float a0 = Tt[r0][kk], a1 = Tt[r0 + 1][kk], a2 = Tt[r0 + 2][kk], a3 = Tt[r0 + 3][kk];
            float4 b = *(const float4*)&Wl[kk][c0];
            acc[0][0] = fmaf(a0, b.x, acc[0][0]); acc[0][1] = fmaf(a0, b.y, acc[0][1]);
            acc[0][2] = fmaf(a0, b.z, acc[0][2]); acc[0][3] = fmaf(a0, b.w, acc[0][3]);
            acc[1][0] = fmaf(a1, b.x, acc[1][0]); acc[1][1] = fmaf(a1, b.y, acc[1][1]);
            acc[1][2] = fmaf(a1, b.z, acc[1][2]); acc[1][3] = fmaf(a1, b.w, acc[1][3]);
            acc[2][0] = fmaf(a2, b.x, acc[2][0]); acc[2][1] = fmaf(a2, b.y, acc[2][1]);
            acc[2][2] = fmaf(a2, b.z, acc[2][2]); acc[2][3] = fmaf(a2, b.w, acc[2][3]);
            acc[3][0] = fmaf(a3, b.x, acc[3][0]); acc[3][1] = fmaf(a3, b.y, acc[3][1]);
            acc[3][2] = fmaf(a3, b.z, acc[3][2]); acc[3][3] = fmaf(a3, b.w, acc[3][3]);
        }
    }

    // bias + relu -> LDS (reuse Tt as H)
    __syncthreads();
#pragma unroll
    for (int i = 0; i < 4; i++) {
#pragma unroll
        for (int jj = 0; jj < 4; jj++) {
            float h = acc[i][jj] + b1l[c0 + jj];
            Tt[r0 + i][c0 + jj] = h > 0.f ? h : 0.f;
        }
    }
    __syncthreads();

    // layer2: 4 threads/node, 4 classes each
    int node = tid >> 2;
    int cg = tid & 3;
    int gnode = base + node;
    if (gnode >= N_NODES) return;
    float l0 = b2l[cg * 4 + 0], l1 = b2l[cg * 4 + 1], l2 = b2l[cg * 4 + 2], l3 = b2l[cg * 4 + 3];
    for (int f = 0; f < 64; f++) {
        float h = Tt[node][f];
        l0 = fmaf(h, W2l[f * 16 + cg * 4 + 0], l0);
        l1 = fmaf(h, W2l[f * 16 + cg * 4 + 1], l1);
        l2 = fmaf(h, W2l[f * 16 + cg * 4 + 2], l2);
        l3 = fmaf(h, W2l[f * 16 + cg * 4 + 3], l3);
    }
    float m = fmaxf(fmaxf(l0, l1), fmaxf(l2, l3));
    m = fmaxf(m, __shfl_xor(m, 1, 64));
    m = fmaxf(m, __shfl_xor(m, 2, 64));
    float e0 = expf(l0 - m), e1 = expf(l1 - m), e2 = expf(l2 - m), e3 = expf(l3 - m);
    float s = e0 + e1 + e2 + e3;
    s += __shfl_xor(s, 1, 64);
    s += __shfl_xor(s, 2, 64);
    float inv = 1.f / s;
    float4 o = make_float4(e0 * inv, e1 * inv, e2 * inv, e3 * inv);
    *(float4*)&y[(size_t)gnode * 16 + cg * 4] = o;
}

// ---------------- launch ----------------

extern "C" void kernel_launch(void* const* d_in, const int* in_sizes, int n_in,
                              void* d_out, int out_size, void* d_ws, size_t ws_size,
                              hipStream_t stream) {
    const float* x  = (const float*)d_in[0];
    const int*   ei = (const int*)d_in[1];
    const float* W1 = (const float*)d_in[2];
    const float* b1 = (const float*)d_in[3];
    const float* W2 = (const float*)d_in[4];
    const float* b2 = (const float*)d_in[5];
    float* y = (float*)d_out;

    char* p = (char*)d_ws;
    auto alloc = [&](size_t bytes) {
        char* q = p;
        p += (bytes + 255) & ~(size_t)255;
        return q;
    };
    int*   deg    = (int*)alloc((size_t)N_NODES * 4);
    float* dinv   = (float*)alloc((size_t)N_NODES * 4);
    int*   rowptr = (int*)alloc((size_t)(N_NODES + 1) * 4);
    int*   bsum   = (int*)alloc(128 * 4);
    int*   cursor = (int*)alloc((size_t)N_NODES * 4);
    int2*  csr_ew = (int2*)alloc((size_t)N_EDGES * 8);
    __half* T     = (__half*)alloc((size_t)K1 * N_NODES * F * 2);  // 8 Chebyshev buffers

    hipMemsetAsync(deg, 0, (size_t)N_NODES * 4, stream);
    hipMemsetAsync(cursor, 0, (size_t)N_NODES * 4, stream);

    int eb = (N_EDGES + 255) / 256;
    int nb = (N_NODES + 255) / 256;
    k_deg<<<eb, 256, 0, stream>>>(ei, deg);
    k_dinv<<<nb, 256, 0, stream>>>(deg, dinv);
    int nblk = (N_NODES + 1023) / 1024;
    k_scan1<<<nblk, 256, 0, stream>>>(deg, rowptr, bsum);
    k_scan2<<<1, 64, 0, stream>>>(bsum, rowptr, nblk);
    k_scan3<<<nblk, 256, 0, stream>>>(rowptr, bsum);
    k_fill<<<eb, 256, 0, stream>>>(ei, dinv, rowptr, cursor, csr_ew);

    const size_t TSZ = (size_t)N_NODES * F;
    __half* Tk[K1];
    for (int k = 0; k < K1; k++) Tk[k] = T + (size_t)k * TSZ;

    // T0 = x (fp16)
    k_cvt<<<(N_NODES * F / 4 + 255) / 256, 256, 0, stream>>>(x, Tk[0]);

    int prop_blocks = (N_NODES + 3) / 4;
    // T1 = L_hat @ T0
    k_prop<<<prop_blocks, 256, 0, stream>>>(rowptr, csr_ew, Tk[0], Tk[0], Tk[1], 1.f, 0.f);
    // Tk = 2*L_hat@T_{k-1} - T_{k-2}
    for (int k = 2; k < K1; k++)
        k_prop<<<prop_blocks, 256, 0, stream>>>(rowptr, csr_ew, Tk[k - 1], Tk[k - 2], Tk[k], 2.f, 1.f);

    int gemm_blocks = (N_NODES + 63) / 64;
    k_fused_out<<<gemm_blocks, 256, 0, stream>>>(T, W1, b1, W2, b2, y);
}

// Round 3
// 608.490 us; speedup vs baseline: 2.3138x; 1.5455x over previous
//
#include <hip/hip_runtime.h>
#include <hip/hip_fp16.h>

#define N_NODES 100000
#define N_EDGES 1600000
#define F 64
#define NCLS 16
#define K1 8

// ---------------- degree / normalization ----------------

__global__ void k_deg(const int* __restrict__ ei, int* __restrict__ deg) {
    int e = blockIdx.x * blockDim.x + threadIdx.x;
    if (e >= N_EDGES) return;
    int r = ei[e], c = ei[N_EDGES + e];
    if (r != c) atomicAdd(&deg[r], 1);
}

__global__ void k_dinv(const int* __restrict__ deg, float* __restrict__ dinv) {
    int i = blockIdx.x * blockDim.x + threadIdx.x;
    if (i >= N_NODES) return;
    int d = deg[i];
    dinv[i] = d > 0 ? rsqrtf((float)d) : 0.f;
}

// ---------------- exclusive scan (rowptr) ----------------
__global__ void k_scan1(const int* __restrict__ deg, int* __restrict__ rowptr, int* __restrict__ bsum) {
    __shared__ int sd[256];
    int tid = threadIdx.x;
    int base = blockIdx.x * 1024 + tid * 4;
    int v[4];
#pragma unroll
    for (int j = 0; j < 4; j++) {
        int idx = base + j;
        v[j] = (idx < N_NODES) ? deg[idx] : 0;
    }
    int s = v[0] + v[1] + v[2] + v[3];
    sd[tid] = s;
    __syncthreads();
    for (int d = 1; d < 256; d <<= 1) {
        int t = (tid >= d) ? sd[tid - d] : 0;
        __syncthreads();
        sd[tid] += t;
        __syncthreads();
    }
    int excl = sd[tid] - s;
    if (tid == 255) bsum[blockIdx.x] = sd[255];
    int run = excl;
#pragma unroll
    for (int j = 0; j < 4; j++) {
        int idx = base + j;
        if (idx < N_NODES) rowptr[idx] = run;
        run += v[j];
    }
}

__global__ void k_scan2(int* __restrict__ bsum, int* __restrict__ rowptr, int nblk) {
    if (threadIdx.x == 0 && blockIdx.x == 0) {
        int acc = 0;
        for (int b = 0; b < nblk; b++) { int t = bsum[b]; bsum[b] = acc; acc += t; }
        rowptr[N_NODES] = acc;
    }
}

__global__ void k_scan3(int* __restrict__ rowptr, const int* __restrict__ bsum) {
    int tid = threadIdx.x;
    int base = blockIdx.x * 1024 + tid * 4;
    int off = bsum[blockIdx.x];
#pragma unroll
    for (int j = 0; j < 4; j++) {
        int idx = base + j;
        if (idx < N_NODES) rowptr[idx] += off;
    }
}

// ---------------- CSR fill: packed (col, weight_bits) ----------------
__global__ void k_fill(const int* __restrict__ ei, const float* __restrict__ dinv,
                       const int* __restrict__ rowptr, int* __restrict__ cursor,
                       int2* __restrict__ csr_ew) {
    int e = blockIdx.x * blockDim.x + threadIdx.x;
    if (e >= N_EDGES) return;
    int r = ei[e], c = ei[N_EDGES + e];
    if (r == c) return;
    int p = rowptr[r] + atomicAdd(&cursor[r], 1);
    float w = -dinv[r] * dinv[c];
    csr_ew[p] = make_int2(c, __float_as_int(w));
}

// ---------------- x fp32 -> fp16 ----------------
__global__ void k_cvt(const float* __restrict__ x, __half* __restrict__ t0) {
    int i = blockIdx.x * blockDim.x + threadIdx.x;
    int base = i * 4;
    if (base >= N_NODES * F) return;
    float4 v = *(const float4*)&x[base];
    __half2 a = __floats2half2_rn(v.x, v.y);
    __half2 b = __floats2half2_rn(v.z, v.w);
    *(__half2*)&t0[base] = a;
    *(__half2*)&t0[base + 2] = b;
}

// ---------------- propagation: dst = alpha*(L_hat @ src) - beta*prev ----------------
// one wave per node, lane = feature. Edge records loaded 64-at-a-time coalesced,
// broadcast via uniform shfl; row gathers unrolled x8 for MLP.
__global__ __launch_bounds__(256) void k_prop(const int* __restrict__ rowptr,
                                              const int2* __restrict__ csr_ew,
                                              const __half* __restrict__ src,
                                              const __half* __restrict__ prev,
                                              __half* __restrict__ dst,
                                              float alpha, float beta) {
    int wid = (int)((blockIdx.x * blockDim.x + threadIdx.x) >> 6);
    int lane = threadIdx.x & 63;
    if (wid >= N_NODES) return;
    int beg = rowptr[wid], end = rowptr[wid + 1];

    float acc0 = 0.f, acc1 = 0.f, acc2 = 0.f, acc3 = 0.f;

    for (int cb = beg; cb < end; cb += 64) {
        int n = end - cb;
        if (n > 64) n = 64;
        int2 e = make_int2(0, 0);
        if (lane < n) e = csr_ew[cb + lane];

        int j = 0;
        for (; j + 7 < n; j += 8) {
            int cc[8];
            float ww[8];
#pragma unroll
            for (int u = 0; u < 8; u++) {
                cc[u] = __shfl(e.x, j + u, 64);
                ww[u] = __int_as_float(__shfl(e.y, j + u, 64));
            }
            float vv[8];
#pragma unroll
            for (int u = 0; u < 8; u++)
                vv[u] = __half2float(src[(size_t)cc[u] * F + lane]);
            acc0 = fmaf(ww[0], vv[0], acc0);
            acc1 = fmaf(ww[1], vv[1], acc1);
            acc2 = fmaf(ww[2], vv[2], acc2);
            acc3 = fmaf(ww[3], vv[3], acc3);
            acc0 = fmaf(ww[4], vv[4], acc0);
            acc1 = fmaf(ww[5], vv[5], acc1);
            acc2 = fmaf(ww[6], vv[6], acc2);
            acc3 = fmaf(ww[7], vv[7], acc3);
        }
        for (; j + 3 < n; j += 4) {
            int cc[4];
            float ww[4];
#pragma unroll
            for (int u = 0; u < 4; u++) {
                cc[u] = __shfl(e.x, j + u, 64);
                ww[u] = __int_as_float(__shfl(e.y, j + u, 64));
            }
            float vv[4];
#pragma unroll
            for (int u = 0; u < 4; u++)
                vv[u] = __half2float(src[(size_t)cc[u] * F + lane]);
            acc0 = fmaf(ww[0], vv[0], acc0);
            acc1 = fmaf(ww[1], vv[1], acc1);
            acc2 = fmaf(ww[2], vv[2], acc2);
            acc3 = fmaf(ww[3], vv[3], acc3);
        }
        for (; j < n; j++) {
            int c0 = __shfl(e.x, j, 64);
            float w0 = __int_as_float(__shfl(e.y, j, 64));
            acc0 = fmaf(w0, __half2float(src[(size_t)c0 * F + lane]), acc0);
        }
    }

    float res = alpha * ((acc0 + acc1) + (acc2 + acc3));
    if (beta != 0.f) res -= beta * __half2float(prev[(size_t)wid * F + lane]);
    dst[(size_t)wid * F + lane] = __float2half(res);
}

// ---------------- fused: out = softmax(relu(sum_k Tx_k @ W1_k + b1) @ W2 + b2) ----------------
__global__ __launch_bounds__(256) void k_fused_out(const __half* __restrict__ T,   // [K1][N][64]
                                                   const float* __restrict__ W1,   // [K1][64][64]
                                                   const float* __restrict__ b1,
                                                   const float* __restrict__ W2,   // [64][16]
                                                   const float* __restrict__ b2,
                                                   float* __restrict__ y) {
    __shared__ float Tt[64][65];
    __shared__ float Wl[64][64];
    __shared__ float W2l[64 * 16];
    __shared__ float b1l[64];
    __shared__ float b2l[16];
    int tid = threadIdx.x;
    int base = blockIdx.x * 64;

    for (int j = tid; j < 64 * 16; j += 256) W2l[j] = W2[j];
    if (tid < 64) b1l[tid] = b1[tid];
    if (tid < 16) b2l[tid] = b2[tid];

    int r0 = (tid >> 4) * 4, c0 = (tid & 15) * 4;
    float acc[4][4] = {};

    for (int k = 0; k < K1; k++) {
        const __half* Tk = T + (size_t)k * N_NODES * F;
        const float* Wk = W1 + (size_t)k * 4096;
        __syncthreads();
#pragma unroll
        for (int j = 0; j < 4; j++) {
            int e = j * 1024 + tid * 4;
            int r = e >> 6, c = e & 63;
            int gr = base + r;
            if (gr < N_NODES) {
                const __half2* p2 = (const __half2*)&Tk[(size_t)gr * F + c];
                float2 fa = __half22float2(p2[0]);
                float2 fb = __half22float2(p2[1]);
                Tt[r][c] = fa.x; Tt[r][c + 1] = fa.y; Tt[r][c + 2] = fb.x; Tt[r][c + 3] = fb.y;
            } else {
                Tt[r][c] = 0.f; Tt[r][c + 1] = 0.f; Tt[r][c + 2] = 0.f; Tt[r][c + 3] = 0.f;
            }
            *(float4*)&Wl[r][c] = *(const float4*)&Wk[e];
        }
        __syncthreads();
        for (int kk = 0; kk < 64; kk++) {
            float a0 = Tt[r0][kk], a1 = Tt[r0 + 1][kk], a2 = Tt[r0 + 2][kk], a3 = Tt[r0 + 3][kk];
            float4 b = *(const float4*)&Wl[kk][c0];
            acc[0][0] = fmaf(a0, b.x, acc[0][0]); acc[0][1] = fmaf(a0, b.y, acc[0][1]);
            acc[0][2] = fmaf(a0, b.z, acc[0][2]); acc[0][3] = fmaf(a0, b.w, acc[0][3]);
            acc[1][0] = fmaf(a1, b.x, acc[1][0]); acc[1][1] = fmaf(a1, b.y, acc[1][1]);
            acc[1][2] = fmaf(a1, b.z, acc[1][2]); acc[1][3] = fmaf(a1, b.w, acc[1][3]);
            acc[2][0] = fmaf(a2, b.x, acc[2][0]); acc[2][1] = fmaf(a2, b.y, acc[2][1]);
            acc[2][2] = fmaf(a2, b.z, acc[2][2]); acc[2][3] = fmaf(a2, b.w, acc[2][3]);
            acc[3][0] = fmaf(a3, b.x, acc[3][0]); acc[3][1] = fmaf(a3, b.y, acc[3][1]);
            acc[3][2] = fmaf(a3, b.z, acc[3][2]); acc[3][3] = fmaf(a3, b.w, acc[3][3]);
        }
    }

    __syncthreads();
#pragma unroll
    for (int i = 0; i < 4; i++) {
#pragma unroll
        for (int jj = 0; jj < 4; jj++) {
            float h = acc[i][jj] + b1l[c0 + jj];
            Tt[r0 + i][c0 + jj] = h > 0.f ? h : 0.f;
        }
    }
    __syncthreads();

    int node = tid >> 2;
    int cg = tid & 3;
    int gnode = base + node;
    if (gnode >= N_NODES) return;
    float l0 = b2l[cg * 4 + 0], l1 = b2l[cg * 4 + 1], l2 = b2l[cg * 4 + 2], l3 = b2l[cg * 4 + 3];
    for (int f = 0; f < 64; f++) {
        float h = Tt[node][f];
        l0 = fmaf(h, W2l[f * 16 + cg * 4 + 0], l0);
        l1 = fmaf(h, W2l[f * 16 + cg * 4 + 1], l1);
        l2 = fmaf(h, W2l[f * 16 + cg * 4 + 2], l2);
        l3 = fmaf(h, W2l[f * 16 + cg * 4 + 3], l3);
    }
    float m = fmaxf(fmaxf(l0, l1), fmaxf(l2, l3));
    m = fmaxf(m, __shfl_xor(m, 1, 64));
    m = fmaxf(m, __shfl_xor(m, 2, 64));
    float e0 = expf(l0 - m), e1 = expf(l1 - m), e2 = expf(l2 - m), e3 = expf(l3 - m);
    float s = e0 + e1 + e2 + e3;
    s += __shfl_xor(s, 1, 64);
    s += __shfl_xor(s, 2, 64);
    float inv = 1.f / s;
    float4 o = make_float4(e0 * inv, e1 * inv, e2 * inv, e3 * inv);
    *(float4*)&y[(size_t)gnode * 16 + cg * 4] = o;
}

// ---------------- launch ----------------

extern "C" void kernel_launch(void* const* d_in, const int* in_sizes, int n_in,
                              void* d_out, int out_size, void* d_ws, size_t ws_size,
                              hipStream_t stream) {
    const float* x  = (const float*)d_in[0];
    const int*   ei = (const int*)d_in[1];
    const float* W1 = (const float*)d_in[2];
    const float* b1 = (const float*)d_in[3];
    const float* W2 = (const float*)d_in[4];
    const float* b2 = (const float*)d_in[5];
    float* y = (float*)d_out;

    char* p = (char*)d_ws;
    auto alloc = [&](size_t bytes) {
        char* q = p;
        p += (bytes + 255) & ~(size_t)255;
        return q;
    };
    int*   deg    = (int*)alloc((size_t)N_NODES * 4);
    float* dinv   = (float*)alloc((size_t)N_NODES * 4);
    int*   rowptr = (int*)alloc((size_t)(N_NODES + 1) * 4);
    int*   bsum   = (int*)alloc(128 * 4);
    int*   cursor = (int*)alloc((size_t)N_NODES * 4);
    int2*  csr_ew = (int2*)alloc((size_t)N_EDGES * 8);
    __half* T     = (__half*)alloc((size_t)K1 * N_NODES * F * 2);

    hipMemsetAsync(deg, 0, (size_t)N_NODES * 4, stream);
    hipMemsetAsync(cursor, 0, (size_t)N_NODES * 4, stream);

    int eb = (N_EDGES + 255) / 256;
    int nb = (N_NODES + 255) / 256;
    k_deg<<<eb, 256, 0, stream>>>(ei, deg);
    k_dinv<<<nb, 256, 0, stream>>>(deg, dinv);
    int nblk = (N_NODES + 1023) / 1024;
    k_scan1<<<nblk, 256, 0, stream>>>(deg, rowptr, bsum);
    k_scan2<<<1, 64, 0, stream>>>(bsum, rowptr, nblk);
    k_scan3<<<nblk, 256, 0, stream>>>(rowptr, bsum);
    k_fill<<<eb, 256, 0, stream>>>(ei, dinv, rowptr, cursor, csr_ew);

    const size_t TSZ = (size_t)N_NODES * F;
    __half* Tk[K1];
    for (int k = 0; k < K1; k++) Tk[k] = T + (size_t)k * TSZ;

    k_cvt<<<(N_NODES * F / 4 + 255) / 256, 256, 0, stream>>>(x, Tk[0]);

    int prop_blocks = (N_NODES + 3) / 4;
    k_prop<<<prop_blocks, 256, 0, stream>>>(rowptr, csr_ew, Tk[0], Tk[0], Tk[1], 1.f, 0.f);
    for (int k = 2; k < K1; k++)
        k_prop<<<prop_blocks, 256, 0, stream>>>(rowptr, csr_ew, Tk[k - 1], Tk[k - 2], Tk[k], 2.f, 1.f);

    int gemm_blocks = (N_NODES + 63) / 64;
    k_fused_out<<<gemm_blocks, 256, 0, stream>>>(T, W1, b1, W2, b2, y);
}

// Round 4
// 525.973 us; speedup vs baseline: 2.6768x; 1.1569x over previous
//
#include <hip/hip_runtime.h>
#include <hip/hip_fp16.h>

#define N_NODES 100000
#define N_EDGES 1600000
#define F 64
#define NCLS 16
#define K1 8

using f16x8 = __attribute__((ext_vector_type(8))) _Float16;
using f32x4 = __attribute__((ext_vector_type(4))) float;

// ---------------- degree / normalization ----------------

__global__ void k_deg(const int* __restrict__ ei, int* __restrict__ deg) {
    int e = blockIdx.x * blockDim.x + threadIdx.x;
    if (e >= N_EDGES) return;
    int r = ei[e], c = ei[N_EDGES + e];
    if (r != c) atomicAdd(&deg[r], 1);
}

__global__ void k_dinv(const int* __restrict__ deg, float* __restrict__ dinv) {
    int i = blockIdx.x * blockDim.x + threadIdx.x;
    if (i >= N_NODES) return;
    int d = deg[i];
    dinv[i] = d > 0 ? rsqrtf((float)d) : 0.f;
}

// ---------------- exclusive scan (rowptr) ----------------
__global__ void k_scan1(const int* __restrict__ deg, int* __restrict__ rowptr, int* __restrict__ bsum) {
    __shared__ int sd[256];
    int tid = threadIdx.x;
    int base = blockIdx.x * 1024 + tid * 4;
    int v[4];
#pragma unroll
    for (int j = 0; j < 4; j++) {
        int idx = base + j;
        v[j] = (idx < N_NODES) ? deg[idx] : 0;
    }
    int s = v[0] + v[1] + v[2] + v[3];
    sd[tid] = s;
    __syncthreads();
    for (int d = 1; d < 256; d <<= 1) {
        int t = (tid >= d) ? sd[tid - d] : 0;
        __syncthreads();
        sd[tid] += t;
        __syncthreads();
    }
    int excl = sd[tid] - s;
    if (tid == 255) bsum[blockIdx.x] = sd[255];
    int run = excl;
#pragma unroll
    for (int j = 0; j < 4; j++) {
        int idx = base + j;
        if (idx < N_NODES) rowptr[idx] = run;
        run += v[j];
    }
}

__global__ void k_scan2(int* __restrict__ bsum, int* __restrict__ rowptr, int nblk) {
    if (threadIdx.x == 0 && blockIdx.x == 0) {
        int acc = 0;
        for (int b = 0; b < nblk; b++) { int t = bsum[b]; bsum[b] = acc; acc += t; }
        rowptr[N_NODES] = acc;
    }
}

__global__ void k_scan3(int* __restrict__ rowptr, const int* __restrict__ bsum) {
    int tid = threadIdx.x;
    int base = blockIdx.x * 1024 + tid * 4;
    int off = bsum[blockIdx.x];
#pragma unroll
    for (int j = 0; j < 4; j++) {
        int idx = base + j;
        if (idx < N_NODES) rowptr[idx] += off;
    }
}

// ---------------- CSR fill: packed (col, weight_bits) ----------------
__global__ void k_fill(const int* __restrict__ ei, const float* __restrict__ dinv,
                       const int* __restrict__ rowptr, int* __restrict__ cursor,
                       int2* __restrict__ csr_ew) {
    int e = blockIdx.x * blockDim.x + threadIdx.x;
    if (e >= N_EDGES) return;
    int r = ei[e], c = ei[N_EDGES + e];
    if (r == c) return;
    int p = rowptr[r] + atomicAdd(&cursor[r], 1);
    float w = -dinv[r] * dinv[c];
    csr_ew[p] = make_int2(c, __float_as_int(w));
}

// ---------------- x fp32 -> fp16 ----------------
__global__ void k_cvt(const float* __restrict__ x, __half* __restrict__ t0) {
    int i = blockIdx.x * blockDim.x + threadIdx.x;
    int base = i * 4;
    if (base >= N_NODES * F) return;
    float4 v = *(const float4*)&x[base];
    __half2 a = __floats2half2_rn(v.x, v.y);
    __half2 b = __floats2half2_rn(v.z, v.w);
    *(__half2*)&t0[base] = a;
    *(__half2*)&t0[base + 2] = b;
}

// ---------------- W1 -> fp16 B-fragment layout ----------------
// Wf flat index t = ((kidx*2+fg)*4 + cb)*64 + lane, 8 f16 each:
//   vals[j] = W1[kidx][fg*32 + (lane>>4)*8 + j][cb*16 + (lane&15)]
__global__ void k_prepW(const float* __restrict__ W1, __half* __restrict__ Wf) {
    int t = blockIdx.x * blockDim.x + threadIdx.x;
    if (t >= K1 * 2 * 4 * 64) return;
    int lane = t & 63;
    int cb = (t >> 6) & 3;
    int fg = (t >> 8) & 1;
    int kidx = t >> 9;
    int col = cb * 16 + (lane & 15);
    int kbase = fg * 32 + (lane >> 4) * 8;
    f16x8 v;
#pragma unroll
    for (int j = 0; j < 8; j++)
        v[j] = (_Float16)W1[kidx * 4096 + (kbase + j) * 64 + col];
    *(f16x8*)(Wf + (size_t)t * 8) = v;
}

// ---------------- propagation: dst = alpha*(L_hat @ src) - beta*prev ----------------
// one wave per node, lane = feature. Edge records loaded 64-at-a-time coalesced,
// broadcast via uniform shfl; row gathers unrolled x8 for MLP.
__global__ __launch_bounds__(256) void k_prop(const int* __restrict__ rowptr,
                                              const int2* __restrict__ csr_ew,
                                              const __half* __restrict__ src,
                                              const __half* __restrict__ prev,
                                              __half* __restrict__ dst,
                                              float alpha, float beta) {
    int wid = (int)((blockIdx.x * blockDim.x + threadIdx.x) >> 6);
    int lane = threadIdx.x & 63;
    if (wid >= N_NODES) return;
    int beg = rowptr[wid], end = rowptr[wid + 1];

    float acc0 = 0.f, acc1 = 0.f, acc2 = 0.f, acc3 = 0.f;

    for (int cb = beg; cb < end; cb += 64) {
        int n = end - cb;
        if (n > 64) n = 64;
        int2 e = make_int2(0, 0);
        if (lane < n) e = csr_ew[cb + lane];

        int j = 0;
        for (; j + 7 < n; j += 8) {
            int cc[8];
            float ww[8];
#pragma unroll
            for (int u = 0; u < 8; u++) {
                cc[u] = __shfl(e.x, j + u, 64);
                ww[u] = __int_as_float(__shfl(e.y, j + u, 64));
            }
            float vv[8];
#pragma unroll
            for (int u = 0; u < 8; u++)
                vv[u] = __half2float(src[(size_t)cc[u] * F + lane]);
            acc0 = fmaf(ww[0], vv[0], acc0);
            acc1 = fmaf(ww[1], vv[1], acc1);
            acc2 = fmaf(ww[2], vv[2], acc2);
            acc3 = fmaf(ww[3], vv[3], acc3);
            acc0 = fmaf(ww[4], vv[4], acc0);
            acc1 = fmaf(ww[5], vv[5], acc1);
            acc2 = fmaf(ww[6], vv[6], acc2);
            acc3 = fmaf(ww[7], vv[7], acc3);
        }
        for (; j + 3 < n; j += 4) {
            int cc[4];
            float ww[4];
#pragma unroll
            for (int u = 0; u < 4; u++) {
                cc[u] = __shfl(e.x, j + u, 64);
                ww[u] = __int_as_float(__shfl(e.y, j + u, 64));
            }
            float vv[4];
#pragma unroll
            for (int u = 0; u < 4; u++)
                vv[u] = __half2float(src[(size_t)cc[u] * F + lane]);
            acc0 = fmaf(ww[0], vv[0], acc0);
            acc1 = fmaf(ww[1], vv[1], acc1);
            acc2 = fmaf(ww[2], vv[2], acc2);
            acc3 = fmaf(ww[3], vv[3], acc3);
        }
        for (; j < n; j++) {
            int c0 = __shfl(e.x, j, 64);
            float w0 = __int_as_float(__shfl(e.y, j, 64));
            acc0 = fmaf(w0, __half2float(src[(size_t)c0 * F + lane]), acc0);
        }
    }

    float res = alpha * ((acc0 + acc1) + (acc2 + acc3));
    if (beta != 0.f) res -= beta * __half2float(prev[(size_t)wid * F + lane]);
    dst[(size_t)wid * F + lane] = __float2half(res);
}

// ---------------- fused MFMA: y = softmax(relu(sum_k Tk@W1k + b1) @ W2 + b2) ----------------
// 64-node tile / block, 4 waves; wave w computes nodes [base+16w, base+16w+16).
// A-fragments straight from global T (16B/lane), B-fragments from pre-swizzled Wf.
__global__ __launch_bounds__(256) void k_fused_mfma(const __half* __restrict__ T,
                                                    const __half* __restrict__ Wf,
                                                    const float* __restrict__ b1,
                                                    const float* __restrict__ W2,
                                                    const float* __restrict__ b2,
                                                    float* __restrict__ y) {
    __shared__ float Ht[64][65];
    __shared__ float W2l[64 * 16];
    __shared__ float b2l[16];
    int tid = threadIdx.x;
    int lane = tid & 63;
    int w = tid >> 6;
    int ln15 = lane & 15;
    int lg = lane >> 4;
    int base = blockIdx.x * 64;

    for (int j = tid; j < 64 * 16; j += 256) W2l[j] = W2[j];
    if (tid < 16) b2l[tid] = b2[tid];

    int nd = base + (w << 4) + ln15;
    if (nd > N_NODES - 1) nd = N_NODES - 1;  // clamp: garbage rows, stores guarded

    f32x4 acc0 = {0.f, 0.f, 0.f, 0.f};
    f32x4 acc1 = {0.f, 0.f, 0.f, 0.f};
    f32x4 acc2 = {0.f, 0.f, 0.f, 0.f};
    f32x4 acc3 = {0.f, 0.f, 0.f, 0.f};

    for (int s = 0; s < 16; s++) {
        int kidx = s >> 1;
        int fg = s & 1;
        f16x8 a = *(const f16x8*)(T + ((size_t)kidx * N_NODES + nd) * F + fg * 32 + lg * 8);
        const __half* wb = Wf + ((size_t)((kidx * 2 + fg) * 4) * 64 + lane) * 8;
        f16x8 b0 = *(const f16x8*)(wb);
        f16x8 b1f = *(const f16x8*)(wb + 64 * 8);
        f16x8 b2f = *(const f16x8*)(wb + 128 * 8);
        f16x8 b3f = *(const f16x8*)(wb + 192 * 8);
        acc0 = __builtin_amdgcn_mfma_f32_16x16x32_f16(a, b0, acc0, 0, 0, 0);
        acc1 = __builtin_amdgcn_mfma_f32_16x16x32_f16(a, b1f, acc1, 0, 0, 0);
        acc2 = __builtin_amdgcn_mfma_f32_16x16x32_f16(a, b2f, acc2, 0, 0, 0);
        acc3 = __builtin_amdgcn_mfma_f32_16x16x32_f16(a, b3f, acc3, 0, 0, 0);
    }

    // relu(acc + b1) -> Ht.  C/D: col = lane&15, row = (lane>>4)*4 + reg
    int hrow = (w << 4) + (lg << 2);
    {
        float bb0 = b1[0 * 16 + ln15];
        float bb1 = b1[1 * 16 + ln15];
        float bb2 = b1[2 * 16 + ln15];
        float bb3 = b1[3 * 16 + ln15];
#pragma unroll
        for (int r = 0; r < 4; r++) {
            float h0 = acc0[r] + bb0;
            float h1 = acc1[r] + bb1;
            float h2 = acc2[r] + bb2;
            float h3 = acc3[r] + bb3;
            Ht[hrow + r][0 * 16 + ln15] = h0 > 0.f ? h0 : 0.f;
            Ht[hrow + r][1 * 16 + ln15] = h1 > 0.f ? h1 : 0.f;
            Ht[hrow + r][2 * 16 + ln15] = h2 > 0.f ? h2 : 0.f;
            Ht[hrow + r][3 * 16 + ln15] = h3 > 0.f ? h3 : 0.f;
        }
    }
    __syncthreads();

    // layer2 + softmax: 4 threads per node
    int node = tid >> 2;
    int cg = tid & 3;
    int gnode = base + node;
    if (gnode >= N_NODES) return;
    float l0 = b2l[cg * 4 + 0], l1 = b2l[cg * 4 + 1], l2 = b2l[cg * 4 + 2], l3 = b2l[cg * 4 + 3];
    for (int f = 0; f < 64; f++) {
        float h = Ht[node][f];
        l0 = fmaf(h, W2l[f * 16 + cg * 4 + 0], l0);
        l1 = fmaf(h, W2l[f * 16 + cg * 4 + 1], l1);
        l2 = fmaf(h, W2l[f * 16 + cg * 4 + 2], l2);
        l3 = fmaf(h, W2l[f * 16 + cg * 4 + 3], l3);
    }
    float m = fmaxf(fmaxf(l0, l1), fmaxf(l2, l3));
    m = fmaxf(m, __shfl_xor(m, 1, 64));
    m = fmaxf(m, __shfl_xor(m, 2, 64));
    float e0 = expf(l0 - m), e1 = expf(l1 - m), e2 = expf(l2 - m), e3 = expf(l3 - m);
    float s = e0 + e1 + e2 + e3;
    s += __shfl_xor(s, 1, 64);
    s += __shfl_xor(s, 2, 64);
    float inv = 1.f / s;
    float4 o = make_float4(e0 * inv, e1 * inv, e2 * inv, e3 * inv);
    *(float4*)&y[(size_t)gnode * 16 + cg * 4] = o;
}

// ---------------- launch ----------------

extern "C" void kernel_launch(void* const* d_in, const int* in_sizes, int n_in,
                              void* d_out, int out_size, void* d_ws, size_t ws_size,
                              hipStream_t stream) {
    const float* x  = (const float*)d_in[0];
    const int*   ei = (const int*)d_in[1];
    const float* W1 = (const float*)d_in[2];
    const float* b1 = (const float*)d_in[3];
    const float* W2 = (const float*)d_in[4];
    const float* b2 = (const float*)d_in[5];
    float* y = (float*)d_out;

    char* p = (char*)d_ws;
    auto alloc = [&](size_t bytes) {
        char* q = p;
        p += (bytes + 255) & ~(size_t)255;
        return q;
    };
    int*   deg    = (int*)alloc((size_t)N_NODES * 4);
    float* dinv   = (float*)alloc((size_t)N_NODES * 4);
    int*   rowptr = (int*)alloc((size_t)(N_NODES + 1) * 4);
    int*   bsum   = (int*)alloc(128 * 4);
    int*   cursor = (int*)alloc((size_t)N_NODES * 4);
    int2*  csr_ew = (int2*)alloc((size_t)N_EDGES * 8);
    __half* T     = (__half*)alloc((size_t)K1 * N_NODES * F * 2);
    __half* Wf    = (__half*)alloc((size_t)K1 * 2 * 4 * 64 * 8 * 2);

    hipMemsetAsync(deg, 0, (size_t)N_NODES * 4, stream);
    hipMemsetAsync(cursor, 0, (size_t)N_NODES * 4, stream);

    int eb = (N_EDGES + 255) / 256;
    int nb = (N_NODES + 255) / 256;
    k_deg<<<eb, 256, 0, stream>>>(ei, deg);
    k_dinv<<<nb, 256, 0, stream>>>(deg, dinv);
    int nblk = (N_NODES + 1023) / 1024;
    k_scan1<<<nblk, 256, 0, stream>>>(deg, rowptr, bsum);
    k_scan2<<<1, 64, 0, stream>>>(bsum, rowptr, nblk);
    k_scan3<<<nblk, 256, 0, stream>>>(rowptr, bsum);
    k_fill<<<eb, 256, 0, stream>>>(ei, dinv, rowptr, cursor, csr_ew);
    k_prepW<<<16, 256, 0, stream>>>(W1, Wf);

    const size_t TSZ = (size_t)N_NODES * F;
    __half* Tk[K1];
    for (int k = 0; k < K1; k++) Tk[k] = T + (size_t)k * TSZ;

    k_cvt<<<(N_NODES * F / 4 + 255) / 256, 256, 0, stream>>>(x, Tk[0]);

    int prop_blocks = (N_NODES + 3) / 4;
    k_prop<<<prop_blocks, 256, 0, stream>>>(rowptr, csr_ew, Tk[0], Tk[0], Tk[1], 1.f, 0.f);
    for (int k = 2; k < K1; k++)
        k_prop<<<prop_blocks, 256, 0, stream>>>(rowptr, csr_ew, Tk[k - 1], Tk[k - 2], Tk[k], 2.f, 1.f);

    int gemm_blocks = (N_NODES + 63) / 64;
    k_fused_mfma<<<gemm_blocks, 256, 0, stream>>>(T, Wf, b1, W2, b2, y);
}